// Round 1
// baseline (229.323 us; speedup 1.0000x reference)
//
#include <hip/hip_runtime.h>

#define HID 512
#define HEADS 8
#define HD 64
#define BATCH 2
#define SEQ 384
#define MROWS (BATCH * SEQ)  // 768

// 2*log2(e): Eq = exp2(C1 * qW) == exp(2*qW)
#define C1 2.8853900817779268f
// log2(e)/8: softmax exponent scale (energy = raw/8)
#define SSCL 0.18033688011112043f

// ---------------------------------------------------------------------------
// prep: fold Ww/Wu into Wq/Wk (per-head block-diagonal), fold biases, vv2=-2vv
// ---------------------------------------------------------------------------
__global__ __launch_bounds__(256) void prep_kernel(
    const float* __restrict__ Wq, const float* __restrict__ bq,
    const float* __restrict__ Wk, const float* __restrict__ bk,
    const float* __restrict__ Ww, const float* __restrict__ bw,
    const float* __restrict__ Wu, const float* __restrict__ bu,
    const float* __restrict__ vv,
    float* __restrict__ wqe, float* __restrict__ wke,
    float* __restrict__ bqe, float* __restrict__ bke,
    float* __restrict__ vv2)
{
    int tid = blockIdx.x * 256 + threadIdx.x;
    if (tid < 262144) {
        int i = tid >> 9, n = tid & 511, h = n >> 6, j = n & 63;
        const float* wrow = Wq + i * HID + h * HD;
        float s = 0.f;
        #pragma unroll 8
        for (int t = 0; t < 64; ++t) s = fmaf(wrow[t], Ww[t * 64 + j], s);
        wqe[tid] = s;
    } else if (tid < 524288) {
        int idx = tid - 262144;
        int i = idx >> 9, n = idx & 511, h = n >> 6, j = n & 63;
        const float* wrow = Wk + i * HID + h * HD;
        float s = 0.f;
        #pragma unroll 8
        for (int t = 0; t < 64; ++t) s = fmaf(wrow[t], Wu[t * 64 + j], s);
        wke[idx] = s;
    } else if (tid < 524800) {
        int n = tid - 524288, h = n >> 6, j = n & 63;
        float s = bw[j];
        for (int t = 0; t < 64; ++t) s = fmaf(bq[h * 64 + t], Ww[t * 64 + j], s);
        bqe[n] = s;
    } else if (tid < 525312) {
        int n = tid - 524800, h = n >> 6, j = n & 63;
        float s = bu[j];
        for (int t = 0; t < 64; ++t) s = fmaf(bk[h * 64 + t], Wu[t * 64 + j], s);
        bke[n] = s;
    } else if (tid < 525376) {
        int d = tid - 525312;
        vv2[d] = -2.0f * vv[d];
    }
}

// ---------------------------------------------------------------------------
// fp32 GEMM: [M=768,K=512] @ [512,512] + bias, optional exp2(scale*y) epilogue
// tile: BM=32, BN=64, BK=32; 256 threads; 2x4 per thread
// ---------------------------------------------------------------------------
__device__ __forceinline__ void gemm_body(
    const float* __restrict__ A, const float* __restrict__ W,
    const float* __restrict__ bias, float* __restrict__ out,
    float expscale, int bm, int bn)
{
    __shared__ float As[32][34];  // [k][m], padded for b64
    __shared__ float Bs[32][68];  // [k][n], padded for b128 (68*4B = 272B, 16B-mult)
    int tid = threadIdx.x;
    int tx = tid & 15, ty = tid >> 4;

    float acc[2][4];
    #pragma unroll
    for (int i = 0; i < 2; ++i)
        #pragma unroll
        for (int j = 0; j < 4; ++j) acc[i][j] = 0.f;

    for (int kt = 0; kt < 16; ++kt) {
        #pragma unroll
        for (int i = 0; i < 4; ++i) {
            int e = tid + i * 256, r = e >> 5, c = e & 31;
            As[c][r] = A[(bm * 32 + r) * HID + kt * 32 + c];
        }
        #pragma unroll
        for (int i = 0; i < 8; ++i) {
            int e = tid + i * 256, r = e >> 6, c = e & 63;
            Bs[r][c] = W[(kt * 32 + r) * HID + bn * 64 + c];
        }
        __syncthreads();
        #pragma unroll
        for (int kk = 0; kk < 32; ++kk) {
            const float2 a = *(const float2*)&As[kk][ty * 2];
            const float4 b4 = *(const float4*)&Bs[kk][tx * 4];
            acc[0][0] = fmaf(a.x, b4.x, acc[0][0]);
            acc[0][1] = fmaf(a.x, b4.y, acc[0][1]);
            acc[0][2] = fmaf(a.x, b4.z, acc[0][2]);
            acc[0][3] = fmaf(a.x, b4.w, acc[0][3]);
            acc[1][0] = fmaf(a.y, b4.x, acc[1][0]);
            acc[1][1] = fmaf(a.y, b4.y, acc[1][1]);
            acc[1][2] = fmaf(a.y, b4.z, acc[1][2]);
            acc[1][3] = fmaf(a.y, b4.w, acc[1][3]);
        }
        __syncthreads();
    }

    int ncol = bn * 64 + tx * 4;
    float4 bias4 = *(const float4*)&bias[ncol];
    #pragma unroll
    for (int i = 0; i < 2; ++i) {
        float4 o;
        o.x = acc[i][0] + bias4.x;
        o.y = acc[i][1] + bias4.y;
        o.z = acc[i][2] + bias4.z;
        o.w = acc[i][3] + bias4.w;
        if (expscale != 0.0f) {
            o.x = __builtin_amdgcn_exp2f(expscale * o.x);
            o.y = __builtin_amdgcn_exp2f(expscale * o.y);
            o.z = __builtin_amdgcn_exp2f(expscale * o.z);
            o.w = __builtin_amdgcn_exp2f(expscale * o.w);
        }
        *(float4*)&out[(size_t)(bm * 32 + ty * 2 + i) * HID + ncol] = o;
    }
}

__global__ __launch_bounds__(256) void proj3_kernel(
    const float* __restrict__ q, const float* __restrict__ k, const float* __restrict__ v,
    const float* __restrict__ wqe, const float* __restrict__ wke, const float* __restrict__ Wv,
    const float* __restrict__ bqe, const float* __restrict__ bke, const float* __restrict__ bv,
    float* __restrict__ Eq, float* __restrict__ Ek, float* __restrict__ V)
{
    int p = blockIdx.z;
    const float* A = (p == 0) ? q : ((p == 1) ? k : v);
    const float* W = (p == 0) ? wqe : ((p == 1) ? wke : Wv);
    const float* bias = (p == 0) ? bqe : ((p == 1) ? bke : bv);
    float* out = (p == 0) ? Eq : ((p == 1) ? Ek : V);
    float es = (p == 2) ? 0.0f : C1;
    gemm_body(A, W, bias, out, es, blockIdx.x, blockIdx.y);
}

__global__ __launch_bounds__(256) void gemm_kernel(
    const float* __restrict__ A, const float* __restrict__ W,
    const float* __restrict__ bias, float* __restrict__ out)
{
    gemm_body(A, W, bias, out, 0.0f, blockIdx.x, blockIdx.y);
}

// ---------------------------------------------------------------------------
// attention: energy (via Eq*Ek + rcp) -> softmax -> write attn -> attn@V
// grid (48, 16): x = q-block of 8 rows, y = b*8+h. 256 thr = 4 waves, 2 q/wave.
// ---------------------------------------------------------------------------
__global__ __launch_bounds__(256) void attn_kernel(
    const float* __restrict__ Eq, const float* __restrict__ Ek,
    const float* __restrict__ V, const float* __restrict__ vv2,
    float* __restrict__ attnOut, float* __restrict__ X)
{
    __shared__ float2 pairEq[8][64];   // {Eq[q][d], vv2[d]}
    __shared__ float2 aP[4][SEQ];      // per-wave attn rows {a_q0, a_q1}

    int b = blockIdx.y >> 3, h = blockIdx.y & 7;
    int qbase = blockIdx.x * 8;
    int tid = threadIdx.x, wave = tid >> 6, lane = tid & 63;

    for (int i = tid; i < 512; i += 256) {
        int qq = i >> 6, d = i & 63;
        pairEq[qq][d] = make_float2(Eq[(size_t)(b * SEQ + qbase + qq) * HID + h * HD + d],
                                    vv2[d]);
    }
    __syncthreads();

    const float* ekbase = Ek + (size_t)b * SEQ * HID + h * HD;
    int q0 = wave * 2, q1 = wave * 2 + 1;
    float e0[6], e1[6];

    #pragma unroll
    for (int kt = 0; kt < 6; ++kt) {
        union { float4 v4[16]; float f[64]; } ek;
        const float4* ekp = (const float4*)(ekbase + (size_t)(kt * 64 + lane) * HID);
        #pragma unroll
        for (int i = 0; i < 16; ++i) ek.v4[i] = ekp[i];
        float r0 = 0.f, r1 = 0.f;
        #pragma unroll
        for (int d = 0; d < 64; ++d) {
            float ekd = ek.f[d];
            float2 p0 = pairEq[q0][d];
            float t0 = fmaf(p0.x, ekd, 1.0f);
            r0 = fmaf(p0.y, __builtin_amdgcn_rcpf(t0), r0);
            float2 p1 = pairEq[q1][d];
            float t1 = fmaf(p1.x, ekd, 1.0f);
            r1 = fmaf(p1.y, __builtin_amdgcn_rcpf(t1), r1);
        }
        e0[kt] = r0; e1[kt] = r1;
    }

    // softmax over k (384 = 6 tiles x 64 lanes), scale 1/8 folded into exp2
    float m0 = e0[0], m1 = e1[0];
    #pragma unroll
    for (int t = 1; t < 6; ++t) { m0 = fmaxf(m0, e0[t]); m1 = fmaxf(m1, e1[t]); }
    #pragma unroll
    for (int off = 1; off < 64; off <<= 1) {
        m0 = fmaxf(m0, __shfl_xor(m0, off));
        m1 = fmaxf(m1, __shfl_xor(m1, off));
    }
    float a0[6], a1[6], s0 = 0.f, s1 = 0.f;
    #pragma unroll
    for (int t = 0; t < 6; ++t) {
        a0[t] = __builtin_amdgcn_exp2f((e0[t] - m0) * SSCL); s0 += a0[t];
        a1[t] = __builtin_amdgcn_exp2f((e1[t] - m1) * SSCL); s1 += a1[t];
    }
    #pragma unroll
    for (int off = 1; off < 64; off <<= 1) {
        s0 += __shfl_xor(s0, off);
        s1 += __shfl_xor(s1, off);
    }
    float z0 = __builtin_amdgcn_rcpf(s0), z1 = __builtin_amdgcn_rcpf(s1);

    size_t abase = (size_t)(b * HEADS + h) * SEQ * SEQ;
    #pragma unroll
    for (int t = 0; t < 6; ++t) {
        float v0 = a0[t] * z0, v1 = a1[t] * z1;
        attnOut[abase + (size_t)(qbase + q0) * SEQ + t * 64 + lane] = v0;
        attnOut[abase + (size_t)(qbase + q1) * SEQ + t * 64 + lane] = v1;
        aP[wave][t * 64 + lane] = make_float2(v0, v1);
    }
    __syncthreads();

    // x[q,d] = sum_k a[k] * V[b,k,h*64+d]; lane = d
    const float* vb = V + (size_t)b * SEQ * HID + h * HD + lane;
    float x0 = 0.f, x1 = 0.f;
    #pragma unroll 4
    for (int k = 0; k < SEQ; ++k) {
        float v = vb[(size_t)k * HID];
        float2 a = aP[wave][k];
        x0 = fmaf(a.x, v, x0);
        x1 = fmaf(a.y, v, x1);
    }
    X[(size_t)(b * SEQ + qbase + q0) * HID + h * HD + lane] = x0;
    X[(size_t)(b * SEQ + qbase + q1) * HID + h * HD + lane] = x1;
}

// ---------------------------------------------------------------------------
extern "C" void kernel_launch(void* const* d_in, const int* in_sizes, int n_in,
                              void* d_out, int out_size, void* d_ws, size_t ws_size,
                              hipStream_t stream)
{
    const float* query = (const float*)d_in[0];
    const float* key   = (const float*)d_in[1];
    const float* value = (const float*)d_in[2];
    const float* Wq = (const float*)d_in[3];
    const float* bq = (const float*)d_in[4];
    const float* Wk = (const float*)d_in[5];
    const float* bk = (const float*)d_in[6];
    const float* Wv = (const float*)d_in[7];
    const float* bv = (const float*)d_in[8];
    const float* Ww = (const float*)d_in[9];
    const float* bw = (const float*)d_in[10];
    const float* Wu = (const float*)d_in[11];
    const float* bu = (const float*)d_in[12];
    const float* vv = (const float*)d_in[13];
    const float* Wo = (const float*)d_in[14];
    const float* bo = (const float*)d_in[15];

    float* out_x    = (float*)d_out;            // [2,384,512] = 393216
    float* out_attn = out_x + (size_t)MROWS * HID;  // [2,8,384,384] = 2359296

    float* ws  = (float*)d_ws;
    float* wqe = ws;                 // 262144
    float* wke = wqe + 262144;       // 262144
    float* bqe = wke + 262144;       // 512
    float* bke = bqe + 512;          // 512
    float* vv2 = bke + 512;          // 64
    float* EqB = vv2 + 64;           // 393216
    float* EkB = EqB + 393216;       // 393216
    float* Vw  = EkB + 393216;       // 393216
    float* Xw  = Vw + 393216;        // 393216  (total ~8.4 MB)

    prep_kernel<<<dim3(2053), 256, 0, stream>>>(Wq, bq, Wk, bk, Ww, bw, Wu, bu, vv,
                                                wqe, wke, bqe, bke, vv2);
    proj3_kernel<<<dim3(24, 8, 3), 256, 0, stream>>>(query, key, value,
                                                     wqe, wke, Wv,
                                                     bqe, bke, bv,
                                                     EqB, EkB, Vw);
    attn_kernel<<<dim3(48, 16), 256, 0, stream>>>(EqB, EkB, Vw, vv2, out_attn, Xw);
    gemm_kernel<<<dim3(24, 8), 256, 0, stream>>>(Xw, Wo, bo, out_x);
}